// Round 6
// baseline (495.478 us; speedup 1.0000x reference)
//
#include <hip/hip_runtime.h>
#include <math.h>

#define WAVE 64
#define FXSCALE 4398046511104.0   // 2^42

typedef float vfloat4 __attribute__((ext_vector_type(4)));

// h[i] = dot(x[i,:], W) in fp64   (one 32-lane half-wave per row, float4 loads)
__global__ void k_h(const float* __restrict__ x, const float* __restrict__ W,
                    double* __restrict__ h, int N, int C) {
    int t = blockIdx.x * blockDim.x + threadIdx.x;
    int row = t >> 5;
    int lane = t & 31;
    if (row >= N) return;
    const float4* xr = (const float4*)(x + (size_t)row * C);
    const float4* w4 = (const float4*)W;
    int C4 = C >> 2;
    double acc = 0.0;
    for (int c = lane; c < C4; c += 32) {
        float4 xv = xr[c];
        float4 wv = w4[c];
        acc += (double)xv.x * (double)wv.x + (double)xv.y * (double)wv.y
             + (double)xv.z * (double)wv.z + (double)xv.w * (double)wv.w;
    }
    #pragma unroll
    for (int o = 16; o > 0; o >>= 1) acc += __shfl_xor(acc, o);
    if (lane == 0) h[row] = acc;
}

// ONE atomic pass: count + CSR-bucket scatter. cnt doubles as degree.
__global__ void k_scatter(const int* __restrict__ erow, const int* __restrict__ ecol,
                          int* __restrict__ cnt, int* __restrict__ bucket,
                          int* __restrict__ ovfList, int* __restrict__ ovfCnt,
                          int E, int CAP, int ovfCap) {
    int e = blockIdx.x * blockDim.x + threadIdx.x;
    if (e >= E) return;
    int c = ecol[e];
    int p = atomicAdd(&cnt[c], 1);
    if (p < CAP) {
        bucket[(size_t)c * CAP + p] = erow[e];
    } else {
        int q = atomicAdd(ovfCnt, 1);
        if (q < ovfCap) ovfList[q] = e;
    }
}

// dis = 1/sqrt(deg+1); hd = h*dis (exact first mul of the old term)
__global__ void k_dis_hd(const int* __restrict__ cnt, const double* __restrict__ h,
                         double* __restrict__ dis, double* __restrict__ hd, int N) {
    int i = blockIdx.x * blockDim.x + threadIdx.x;
    if (i >= N) return;
    double d = 1.0 / sqrt((double)cnt[i] + 1.0);
    dis[i] = d;
    hd[i] = h[i] * d;
}

// overflow edges (rare/none): fixed-point atomics, order-free deterministic
__global__ void k_ovf(const int* __restrict__ erow, const int* __restrict__ ecol,
                      const double* __restrict__ hd, const double* __restrict__ dis,
                      const int* __restrict__ ovfList, const int* __restrict__ ovfCnt,
                      unsigned long long* __restrict__ ovfAgg, int ovfCap) {
    int q = blockIdx.x * blockDim.x + threadIdx.x;
    int n = ovfCnt[0];
    if (n > ovfCap) n = ovfCap;
    if (q >= n) return;
    int e = ovfList[q];
    int r = erow[e], c = ecol[e];
    long long qq = __double2ll_rn(hd[r] * dis[c] * FXSCALE);
    atomicAdd(&ovfAgg[c], (unsigned long long)qq);
}

// atomic-free gather-reduce; int64 fixed-point => bit-identical to sharded-atomic sum.
// Fuses score + tanh.
__global__ void k_reduce_score(const int* __restrict__ cnt, const int* __restrict__ bucket,
                               const double* __restrict__ h, const double* __restrict__ dis,
                               const double* __restrict__ hd,
                               const unsigned long long* __restrict__ ovfAgg,
                               const float* __restrict__ bptr,
                               float* __restrict__ score32, float* __restrict__ tg,
                               int N, int CAP) {
    int i = blockIdx.x * blockDim.x + threadIdx.x;
    if (i >= N) return;
    int c = cnt[i];
    int m = c < CAP ? c : CAP;
    long long acc = (long long)ovfAgg[i];
    const int* b = bucket + (size_t)i * CAP;
    double dc = dis[i];
    for (int j = 0; j < m; j++) {
        int r = b[j];
        acc += __double2ll_rn(hd[r] * dc * FXSCALE);   // == round_fx(((h*dis_r)*dis_c)*FX)
    }
    double agg = (double)acc / FXSCALE;
    double sc = (agg + h[i] * (dc * dc)) + (double)bptr[0];
    score32[i] = (float)sc;
    tg[i] = (float)tanh(sc);
}

// One THREAD per segment — numerics byte-identical to the passing round-3 kernel.
__global__ void k_seg_np(const float* __restrict__ score32, const int* __restrict__ starts,
                         float* __restrict__ p32, int* __restrict__ keepI,
                         const int* __restrict__ alphaPtr, int N, int S) {
    int g = blockIdx.x * blockDim.x + threadIdx.x;
    if (g >= S) return;
    int st = starts[g];
    int en = (g == S - 1) ? N : starts[g + 1];
    if (en <= st) return;

    int ai = alphaPtr[0];
    float alpha = (ai >= 0 && ai < 1000000) ? (float)ai : __int_as_float(ai);

    float m = -3.402823466e38f;
    for (int i = st; i < en; i++) m = fmaxf(m, score32[i]);

    float Z = 0.0f;
    for (int i = st; i < en; i++) {
        float dm = __fsub_rn(score32[i], m);
        float e = (float)exp((double)dm);   // correctly-rounded fp32 exp
        p32[i] = e;
        Z = __fadd_rn(Z, e);
    }

    float sp = 0.0f, sq = 0.0f, pm = -3.402823466e38f;
    for (int i = st; i < en; i++) {
        float p = __fdiv_rn(p32[i], Z);
        p32[i] = p;
        sp = __fadd_rn(sp, p);
        sq = __fadd_rn(sq, __fmul_rn(p, p));
        pm = fmaxf(pm, p);
    }

    float cnt_ = (float)(en - st);
    float mean = __fdiv_rn(sp, cnt_);
    float var = __fsub_rn(__fdiv_rn(sq, cnt_), __fmul_rn(mean, mean));
    float sd = sqrtf(fmaxf(var, 0.0f));
    float cutoff = __fsub_rn(pm, __fmul_rn(alpha, sd));

    for (int i = st; i < en; i++) keepI[i] = (p32[i] >= cutoff) ? 1 : 0;
}

__global__ void k_union(const int* __restrict__ n1, const int* __restrict__ n2,
                        const int* __restrict__ sent, int* __restrict__ keepI, int S) {
    int i = blockIdx.x * blockDim.x + threadIdx.x;
    if (i >= S) return;
    keepI[n1[i]] = 1;
    keepI[n2[i]] = 1;
    keepI[sent[i]] = 1;
}

#define SCAN_CHUNK 2048  // 256 threads * 8

__global__ void k_scanA(const int* __restrict__ keepI, int* __restrict__ bs, int N) {
    int tid = threadIdx.x;
    long base = (long)blockIdx.x * SCAN_CHUNK + (long)tid * 8;
    int s = 0;
    #pragma unroll
    for (int k = 0; k < 8; k++) { long i = base + k; if (i < N) s += keepI[i]; }
    __shared__ int sm[256];
    sm[tid] = s; __syncthreads();
    for (int off = 128; off > 0; off >>= 1) {
        if (tid < off) sm[tid] += sm[tid + off];
        __syncthreads();
    }
    if (tid == 0) bs[blockIdx.x] = sm[0];
}

__global__ void k_scanB(const int* __restrict__ bs, int* __restrict__ bo, int nb) {
    __shared__ int sm[256];
    __shared__ int carrySh;
    int tid = threadIdx.x;
    if (tid == 0) carrySh = 0;
    __syncthreads();
    for (int base = 0; base < nb; base += 256) {
        int i = base + tid;
        int v = (i < nb) ? bs[i] : 0;
        sm[tid] = v; __syncthreads();
        for (int off = 1; off < 256; off <<= 1) {
            int t = (tid >= off) ? sm[tid - off] : 0;
            __syncthreads();
            sm[tid] += t;
            __syncthreads();
        }
        int incl = sm[tid];
        int total = sm[255];
        int carry = carrySh;
        if (i < nb) bo[i] = carry + incl - v;
        __syncthreads();
        if (tid == 0) carrySh = carry + total;
        __syncthreads();
    }
}

__global__ void k_scanC(const int* __restrict__ keepI, const int* __restrict__ bo,
                        int* __restrict__ pos, float* __restrict__ o_keep, int N) {
    int tid = threadIdx.x;
    long base = (long)blockIdx.x * SCAN_CHUNK + (long)tid * 8;
    int v[8];
    int th = 0;
    #pragma unroll
    for (int k = 0; k < 8; k++) {
        long i = base + k;
        v[k] = (i < N) ? keepI[i] : 0;
        th += v[k];
    }
    __shared__ int sm[256];
    sm[tid] = th; __syncthreads();
    for (int off = 1; off < 256; off <<= 1) {
        int t = (tid >= off) ? sm[tid - off] : 0;
        __syncthreads();
        sm[tid] += t;
        __syncthreads();
    }
    int excl = sm[tid] - th;
    int run = bo[blockIdx.x] + excl;
    #pragma unroll
    for (int k = 0; k < 8; k++) {
        long i = base + k;
        if (i < N) {
            pos[i] = run + v[k] - 1;
            o_keep[i] = v[k] ? 1.0f : 0.0f;
            run += v[k];
        }
    }
}

// fused outputs: [0, nxb) -> x_out float4s; [nxb, nxb+neb) -> edges; rest -> nodes
__global__ void k_out(const float4* __restrict__ x4, const int* __restrict__ keepI,
                      const float* __restrict__ tg, float* __restrict__ o_x, long total4,
                      const int* __restrict__ erow, const int* __restrict__ ecol,
                      const int* __restrict__ pos,
                      float* __restrict__ o_edge, float* __restrict__ o_ekeep, int E,
                      const int* __restrict__ n1, const int* __restrict__ n2,
                      const int* __restrict__ sent,
                      float* __restrict__ o_n1, float* __restrict__ o_n2,
                      float* __restrict__ o_sent, int S,
                      int nxb, int neb) {
    int b = blockIdx.x;
    if (b < nxb) {
        long idx = (long)b * blockDim.x + threadIdx.x;
        if (idx >= total4) return;
        int row = (int)(idx >> 5);   // C/4 = 32 float4 per row
        int kept = keepI[row];
        float g = kept ? tg[row] : 0.0f;
        float4 v = x4[idx];
        vfloat4 r = { v.x * g, v.y * g, v.z * g, v.w * g };
        __builtin_nontemporal_store(r, (vfloat4*)o_x + idx);
    } else if (b < nxb + neb) {
        int e = (b - nxb) * blockDim.x + threadIdx.x;
        if (e >= E) return;
        int r = erow[e], c = ecol[e];
        bool ek = keepI[r] && keepI[c];
        __builtin_nontemporal_store(ek ? (float)pos[r] : -1.0f, &o_edge[e]);
        __builtin_nontemporal_store(ek ? (float)pos[c] : -1.0f, &o_edge[(size_t)E + e]);
        __builtin_nontemporal_store(ek ? 1.0f : 0.0f, &o_ekeep[e]);
    } else {
        int i = (b - nxb - neb) * blockDim.x + threadIdx.x;
        if (i >= S) return;
        o_n1[i] = (float)pos[n1[i]];
        o_n2[i] = (float)pos[n2[i]];
        o_sent[i] = (float)pos[sent[i]];
    }
}

extern "C" void kernel_launch(void* const* d_in, const int* in_sizes, int n_in,
                              void* d_out, int out_size, void* d_ws, size_t ws_size,
                              hipStream_t stream) {
    const float* x    = (const float*)d_in[0];
    const int*   eidx = (const int*)d_in[1];
    const int*   n1   = (const int*)d_in[2];
    const int*   n2   = (const int*)d_in[3];
    const int*   sent = (const int*)d_in[4];
    const float* W    = (const float*)d_in[5];
    const float* bp   = (const float*)d_in[6];
    const int*   alphaPtr = (const int*)d_in[7];

    int C = in_sizes[5];                 // W is [C,1]
    int N = in_sizes[0] / C;
    int E = in_sizes[1] / 2;
    int S = in_sizes[2];

    const int* erow = eidx;
    const int* ecol = eidx + E;

    // fixed per-node buffers: cnt(4)+ovfAgg(8) [zeroed] + h,dis,hd(24) + score,p32,tg,keep,pos(20)
    size_t fixedBytes = (size_t)N * 56 + (1 << 20);
    // pick bucket capacity + overflow list size that fit ws
    int CAP = 64, ovfCap = 1 << 16;
    if (fixedBytes + (size_t)CAP * N * 4 + (size_t)ovfCap * 4 > ws_size) {
        CAP = 32; ovfCap = 1 << 20;
        if (fixedBytes + (size_t)CAP * N * 4 + (size_t)ovfCap * 4 > ws_size) {
            CAP = 16; ovfCap = 1 << 22;
        }
    }

    // workspace layout (cnt+ovfAgg+ovfCnt contiguous for a single memset)
    char* ws = (char*)d_ws;
    size_t off = 0;
    auto alloc = [&](size_t bytes) { void* p = ws + off; off += (bytes + 255) & ~(size_t)255; return p; };
    int*   cnt    = (int*)  alloc((size_t)N * 4);
    unsigned long long* ovfAgg = (unsigned long long*)alloc((size_t)N * 8);
    int*   ovfCnt = (int*)  alloc(256);
    size_t zeroBytes = (size_t)((char*)ovfCnt + 256 - (char*)cnt);
    int*   bucket = (int*)  alloc((size_t)CAP * N * 4);
    int*   ovfList= (int*)  alloc((size_t)ovfCap * 4);
    double* h     = (double*)alloc((size_t)N * 8);
    double* dis   = (double*)alloc((size_t)N * 8);
    double* hd    = (double*)alloc((size_t)N * 8);
    float* score32 = (float*)alloc((size_t)N * 4);
    float* p32    = (float*)alloc((size_t)N * 4);
    float* tg     = (float*)alloc((size_t)N * 4);
    int*   keepI  = (int*)  alloc((size_t)N * 4);
    int*   pos    = (int*)  alloc((size_t)N * 4);
    int nb = (N + SCAN_CHUNK - 1) / SCAN_CHUNK;
    int*   bs     = (int*)  alloc((size_t)nb * 4);
    int*   bo     = (int*)  alloc((size_t)nb * 4);

    // output layout (all float32, concatenated)
    float* o_x     = (float*)d_out;
    float* o_edge  = o_x + (size_t)N * C;
    float* o_keep  = o_edge + 2 * (size_t)E;
    float* o_ekeep = o_keep + N;
    float* o_n1    = o_ekeep + E;
    float* o_n2    = o_n1 + S;
    float* o_sent  = o_n2 + S;

    (void)hipMemsetAsync(cnt, 0, zeroBytes, stream);

    k_h<<<(N * 32 + 255) / 256, 256, 0, stream>>>(x, W, h, N, C);
    k_scatter<<<(E + 255) / 256, 256, 0, stream>>>(erow, ecol, cnt, bucket, ovfList, ovfCnt, E, CAP, ovfCap);
    k_dis_hd<<<(N + 255) / 256, 256, 0, stream>>>(cnt, h, dis, hd, N);
    k_ovf<<<(ovfCap + 255) / 256, 256, 0, stream>>>(erow, ecol, hd, dis, ovfList, ovfCnt, ovfAgg, ovfCap);
    k_reduce_score<<<(N + 255) / 256, 256, 0, stream>>>(cnt, bucket, h, dis, hd, ovfAgg, bp, score32, tg, N, CAP);
    k_seg_np<<<(S + 255) / 256, 256, 0, stream>>>(score32, n1, p32, keepI, alphaPtr, N, S);
    k_union<<<(S + 255) / 256, 256, 0, stream>>>(n1, n2, sent, keepI, S);
    k_scanA<<<nb, 256, 0, stream>>>(keepI, bs, N);
    k_scanB<<<1, 256, 0, stream>>>(bs, bo, nb);
    k_scanC<<<nb, 256, 0, stream>>>(keepI, bo, pos, o_keep, N);

    long total4 = (long)N * (C / 4);
    int nxb = (int)((total4 + 255) / 256);
    int neb = (E + 255) / 256;
    int nsb = (S + 255) / 256;
    k_out<<<nxb + neb + nsb, 256, 0, stream>>>(
        (const float4*)x, keepI, tg, o_x, total4,
        erow, ecol, pos, o_edge, o_ekeep, E,
        n1, n2, sent, o_n1, o_n2, o_sent, S, nxb, neb);
}

// Round 7
// 281.122 us; speedup vs baseline: 1.7625x; 1.7625x over previous
//
#include <hip/hip_runtime.h>
#include <math.h>

#define WAVE 64
#define FXSCALE 4398046511104.0   // 2^42
#define WINDOW 7936               // nodes per col-bin (LDS u64[WINDOW] = 63.5 KB)
#define NBMAX 32

typedef float vfloat4 __attribute__((ext_vector_type(4)));

// h[i] = dot(x[i,:], W) in fp64   (one 32-lane half-wave per row, float4 loads)
__global__ void k_h(const float* __restrict__ x, const float* __restrict__ W,
                    double* __restrict__ h, int N, int C) {
    int t = blockIdx.x * blockDim.x + threadIdx.x;
    int row = t >> 5;
    int lane = t & 31;
    if (row >= N) return;
    const float4* xr = (const float4*)(x + (size_t)row * C);
    const float4* w4 = (const float4*)W;
    int C4 = C >> 2;
    double acc = 0.0;
    for (int c = lane; c < C4; c += 32) {
        float4 xv = xr[c];
        float4 wv = w4[c];
        acc += (double)xv.x * (double)wv.x + (double)xv.y * (double)wv.y
             + (double)xv.z * (double)wv.z + (double)xv.w * (double)wv.w;
    }
    #pragma unroll
    for (int o = 16; o > 0; o >>= 1) acc += __shfl_xor(acc, o);
    if (lane == 0) h[row] = acc;
}

// bin histogram: LDS counters, one global atomic per (block,bin)
__global__ void k_hist(const int* __restrict__ ecol, int* __restrict__ binCnt,
                       int E, int NB) {
    __shared__ int cnt[NBMAX];
    int tid = threadIdx.x;
    if (tid < NBMAX) cnt[tid] = 0;
    __syncthreads();
    for (long e = (long)blockIdx.x * blockDim.x + tid; e < E; e += (long)gridDim.x * blockDim.x)
        atomicAdd(&cnt[ecol[e] / WINDOW], 1);
    __syncthreads();
    if (tid < NB && cnt[tid] > 0) atomicAdd(&binCnt[tid], cnt[tid]);
}

// exclusive scan of 26 bins + init write cursors (1 thread)
__global__ void k_off(const int* __restrict__ binCnt, int* __restrict__ binOff,
                      int* __restrict__ binWr, int NB) {
    if (threadIdx.x != 0 || blockIdx.x != 0) return;
    int acc = 0;
    for (int i = 0; i < NB; i++) {
        binOff[i] = acc;
        binWr[i] = acc;
        acc += binCnt[i];
    }
    binOff[NB] = acc;
}

// partition edges by col-window: one batch of 2048 edges per block.
// LDS rank assignment + one global cursor atomic per (block,bin).
__global__ void k_bin(const int* __restrict__ erow, const int* __restrict__ ecol,
                      int* __restrict__ binWr, int* __restrict__ binnedRow,
                      unsigned short* __restrict__ binnedCol16, int E, int NB) {
    __shared__ int cnt[NBMAX];
    __shared__ int base[NBMAX];
    int tid = threadIdx.x;
    if (tid < NBMAX) cnt[tid] = 0;
    __syncthreads();
    long b0 = (long)blockIdx.x * 2048;
    int bArr[8], rArr[8], rowA[8], colA[8];
    #pragma unroll
    for (int k = 0; k < 8; k++) {
        long e = b0 + (long)k * 256 + tid;
        if (e < E) {
            int c = ecol[e];
            int b = c / WINDOW;
            bArr[k] = b; rowA[k] = erow[e]; colA[k] = c - b * WINDOW;
            rArr[k] = atomicAdd(&cnt[b], 1);
        } else bArr[k] = -1;
    }
    __syncthreads();
    if (tid < NB && cnt[tid] > 0) base[tid] = atomicAdd(&binWr[tid], cnt[tid]);
    __syncthreads();
    #pragma unroll
    for (int k = 0; k < 8; k++) {
        if (bArr[k] >= 0) {
            int idx = base[bArr[k]] + rArr[k];
            binnedRow[idx] = rowA[k];
            binnedCol16[idx] = (unsigned short)colA[k];
        }
    }
}

// per-(bin,m) LDS degree histogram -> coalesced partial store (no global atomics)
__global__ void k_degb(const unsigned short* __restrict__ binnedCol16,
                       const int* __restrict__ binOff,
                       unsigned int* __restrict__ partialDeg, int N, int Md) {
    __shared__ unsigned int cnt[WINDOW];
    int bin = blockIdx.x / Md, m = blockIdx.x % Md;
    int tid = threadIdx.x;
    for (int i = tid; i < WINDOW; i += blockDim.x) cnt[i] = 0;
    __syncthreads();
    int st = binOff[bin], en = binOff[bin + 1];
    for (int idx = st + m * (int)blockDim.x + tid; idx < en; idx += Md * (int)blockDim.x)
        atomicAdd(&cnt[binnedCol16[idx]], 1u);
    __syncthreads();
    int wb = bin * WINDOW;
    for (int i = tid; i < WINDOW && wb + i < N; i += blockDim.x)
        partialDeg[(size_t)m * N + wb + i] = cnt[i];
}

// dis = 1/sqrt(deg+1); hd = h*dis
__global__ void k_dis_hd(const unsigned int* __restrict__ partialDeg,
                         const double* __restrict__ h,
                         double* __restrict__ dis, double* __restrict__ hd,
                         int N, int Md) {
    int i = blockIdx.x * blockDim.x + threadIdx.x;
    if (i >= N) return;
    unsigned int dsum = 0;
    for (int m = 0; m < Md; m++) dsum += partialDeg[(size_t)m * N + i];
    double d = 1.0 / sqrt((double)dsum + 1.0);
    dis[i] = d;
    hd[i] = h[i] * d;
}

// per-(bin,m) LDS u64 fixed-point accumulate -> coalesced partial store.
// Per-term quantization identical to prior passing rounds => bit-identical score.
__global__ void k_aggb(const int* __restrict__ binnedRow,
                       const unsigned short* __restrict__ binnedCol16,
                       const int* __restrict__ binOff,
                       const double* __restrict__ hd, const double* __restrict__ dis,
                       unsigned long long* __restrict__ partialAgg, int N, int Ma) {
    __shared__ unsigned long long acc[WINDOW];   // 63.5 KB
    int bin = blockIdx.x / Ma, m = blockIdx.x % Ma;
    int tid = threadIdx.x;
    for (int i = tid; i < WINDOW; i += blockDim.x) acc[i] = 0ULL;
    __syncthreads();
    int st = binOff[bin], en = binOff[bin + 1];
    int wb = bin * WINDOW;
    for (int idx = st + m * (int)blockDim.x + tid; idx < en; idx += Ma * (int)blockDim.x) {
        int r = binnedRow[idx];
        int c16 = binnedCol16[idx];
        long long q = __double2ll_rn(hd[r] * dis[wb + c16] * FXSCALE);
        atomicAdd(&acc[c16], (unsigned long long)q);
    }
    __syncthreads();
    for (int i = tid; i < WINDOW && wb + i < N; i += blockDim.x)
        partialAgg[(size_t)m * N + wb + i] = acc[i];
}

// score (fp64, rounded to fp32) ; tg = tanh(score) fp32
__global__ void k_score(const unsigned long long* __restrict__ partialAgg,
                        const double* __restrict__ h, const double* __restrict__ dis,
                        const float* __restrict__ bptr,
                        float* __restrict__ score32, float* __restrict__ tg,
                        int N, int Ma) {
    int i = blockIdx.x * blockDim.x + threadIdx.x;
    if (i >= N) return;
    long long acc = 0;
    for (int m = 0; m < Ma; m++) acc += (long long)partialAgg[(size_t)m * N + i];
    double agg = (double)acc / FXSCALE;
    double d = dis[i];
    double sc = (agg + h[i] * (d * d)) + (double)bptr[0];
    score32[i] = (float)sc;
    tg[i] = (float)tanh(sc);
}

// One THREAD per segment — numerics byte-identical to the passing round-3 kernel.
__global__ void k_seg_np(const float* __restrict__ score32, const int* __restrict__ starts,
                         float* __restrict__ p32, int* __restrict__ keepI,
                         const int* __restrict__ alphaPtr, int N, int S) {
    int g = blockIdx.x * blockDim.x + threadIdx.x;
    if (g >= S) return;
    int st = starts[g];
    int en = (g == S - 1) ? N : starts[g + 1];
    if (en <= st) return;

    int ai = alphaPtr[0];
    float alpha = (ai >= 0 && ai < 1000000) ? (float)ai : __int_as_float(ai);

    float m = -3.402823466e38f;
    for (int i = st; i < en; i++) m = fmaxf(m, score32[i]);

    float Z = 0.0f;
    for (int i = st; i < en; i++) {
        float dm = __fsub_rn(score32[i], m);
        float e = (float)exp((double)dm);   // correctly-rounded fp32 exp
        p32[i] = e;
        Z = __fadd_rn(Z, e);
    }

    float sp = 0.0f, sq = 0.0f, pm = -3.402823466e38f;
    for (int i = st; i < en; i++) {
        float p = __fdiv_rn(p32[i], Z);
        p32[i] = p;
        sp = __fadd_rn(sp, p);
        sq = __fadd_rn(sq, __fmul_rn(p, p));
        pm = fmaxf(pm, p);
    }

    float cnt_ = (float)(en - st);
    float mean = __fdiv_rn(sp, cnt_);
    float var = __fsub_rn(__fdiv_rn(sq, cnt_), __fmul_rn(mean, mean));
    float sd = sqrtf(fmaxf(var, 0.0f));
    float cutoff = __fsub_rn(pm, __fmul_rn(alpha, sd));

    for (int i = st; i < en; i++) keepI[i] = (p32[i] >= cutoff) ? 1 : 0;
}

__global__ void k_union(const int* __restrict__ n1, const int* __restrict__ n2,
                        const int* __restrict__ sent, int* __restrict__ keepI, int S) {
    int i = blockIdx.x * blockDim.x + threadIdx.x;
    if (i >= S) return;
    keepI[n1[i]] = 1;
    keepI[n2[i]] = 1;
    keepI[sent[i]] = 1;
}

#define SCAN_CHUNK 2048  // 256 threads * 8

__global__ void k_scanA(const int* __restrict__ keepI, int* __restrict__ bs, int N) {
    int tid = threadIdx.x;
    long base = (long)blockIdx.x * SCAN_CHUNK + (long)tid * 8;
    int s = 0;
    #pragma unroll
    for (int k = 0; k < 8; k++) { long i = base + k; if (i < N) s += keepI[i]; }
    __shared__ int sm[256];
    sm[tid] = s; __syncthreads();
    for (int off = 128; off > 0; off >>= 1) {
        if (tid < off) sm[tid] += sm[tid + off];
        __syncthreads();
    }
    if (tid == 0) bs[blockIdx.x] = sm[0];
}

__global__ void k_scanB(const int* __restrict__ bs, int* __restrict__ bo, int nb) {
    __shared__ int sm[256];
    __shared__ int carrySh;
    int tid = threadIdx.x;
    if (tid == 0) carrySh = 0;
    __syncthreads();
    for (int base = 0; base < nb; base += 256) {
        int i = base + tid;
        int v = (i < nb) ? bs[i] : 0;
        sm[tid] = v; __syncthreads();
        for (int off = 1; off < 256; off <<= 1) {
            int t = (tid >= off) ? sm[tid - off] : 0;
            __syncthreads();
            sm[tid] += t;
            __syncthreads();
        }
        int incl = sm[tid];
        int total = sm[255];
        int carry = carrySh;
        if (i < nb) bo[i] = carry + incl - v;
        __syncthreads();
        if (tid == 0) carrySh = carry + total;
        __syncthreads();
    }
}

__global__ void k_scanC(const int* __restrict__ keepI, const int* __restrict__ bo,
                        int* __restrict__ pos, float* __restrict__ o_keep, int N) {
    int tid = threadIdx.x;
    long base = (long)blockIdx.x * SCAN_CHUNK + (long)tid * 8;
    int v[8];
    int th = 0;
    #pragma unroll
    for (int k = 0; k < 8; k++) {
        long i = base + k;
        v[k] = (i < N) ? keepI[i] : 0;
        th += v[k];
    }
    __shared__ int sm[256];
    sm[tid] = th; __syncthreads();
    for (int off = 1; off < 256; off <<= 1) {
        int t = (tid >= off) ? sm[tid - off] : 0;
        __syncthreads();
        sm[tid] += t;
        __syncthreads();
    }
    int excl = sm[tid] - th;
    int run = bo[blockIdx.x] + excl;
    #pragma unroll
    for (int k = 0; k < 8; k++) {
        long i = base + k;
        if (i < N) {
            pos[i] = run + v[k] - 1;
            o_keep[i] = v[k] ? 1.0f : 0.0f;
            run += v[k];
        }
    }
}

// fused outputs: [0, nxb) -> x_out float4s; [nxb, nxb+neb) -> edges; rest -> nodes
__global__ void k_out(const float4* __restrict__ x4, const int* __restrict__ keepI,
                      const float* __restrict__ tg, float* __restrict__ o_x, long total4,
                      const int* __restrict__ erow, const int* __restrict__ ecol,
                      const int* __restrict__ pos,
                      float* __restrict__ o_edge, float* __restrict__ o_ekeep, int E,
                      const int* __restrict__ n1, const int* __restrict__ n2,
                      const int* __restrict__ sent,
                      float* __restrict__ o_n1, float* __restrict__ o_n2,
                      float* __restrict__ o_sent, int S,
                      int nxb, int neb) {
    int b = blockIdx.x;
    if (b < nxb) {
        long idx = (long)b * blockDim.x + threadIdx.x;
        if (idx >= total4) return;
        int row = (int)(idx >> 5);   // C/4 = 32 float4 per row
        int kept = keepI[row];
        float g = kept ? tg[row] : 0.0f;
        float4 v = x4[idx];
        vfloat4 r = { v.x * g, v.y * g, v.z * g, v.w * g };
        __builtin_nontemporal_store(r, (vfloat4*)o_x + idx);
    } else if (b < nxb + neb) {
        int e = (b - nxb) * blockDim.x + threadIdx.x;
        if (e >= E) return;
        int r = erow[e], c = ecol[e];
        bool ek = keepI[r] && keepI[c];
        __builtin_nontemporal_store(ek ? (float)pos[r] : -1.0f, &o_edge[e]);
        __builtin_nontemporal_store(ek ? (float)pos[c] : -1.0f, &o_edge[(size_t)E + e]);
        __builtin_nontemporal_store(ek ? 1.0f : 0.0f, &o_ekeep[e]);
    } else {
        int i = (b - nxb - neb) * blockDim.x + threadIdx.x;
        if (i >= S) return;
        o_n1[i] = (float)pos[n1[i]];
        o_n2[i] = (float)pos[n2[i]];
        o_sent[i] = (float)pos[sent[i]];
    }
}

extern "C" void kernel_launch(void* const* d_in, const int* in_sizes, int n_in,
                              void* d_out, int out_size, void* d_ws, size_t ws_size,
                              hipStream_t stream) {
    const float* x    = (const float*)d_in[0];
    const int*   eidx = (const int*)d_in[1];
    const int*   n1   = (const int*)d_in[2];
    const int*   n2   = (const int*)d_in[3];
    const int*   sent = (const int*)d_in[4];
    const float* W    = (const float*)d_in[5];
    const float* bp   = (const float*)d_in[6];
    const int*   alphaPtr = (const int*)d_in[7];

    int C = in_sizes[5];                 // W is [C,1]
    int N = in_sizes[0] / C;
    int E = in_sizes[1] / 2;
    int S = in_sizes[2];

    const int* erow = eidx;
    const int* ecol = eidx + E;

    int NB = (N + WINDOW - 1) / WINDOW;  // 26 for N=200000
    const int Md = 8, Ma = 8;

    // workspace layout
    char* ws = (char*)d_ws;
    size_t off = 0;
    auto alloc = [&](size_t bytes) { void* p = ws + off; off += (bytes + 255) & ~(size_t)255; return p; };
    int*   binCnt = (int*)  alloc(NBMAX * 4);          // zeroed
    int*   binOff = (int*)  alloc((NBMAX + 1) * 4);
    int*   binWr  = (int*)  alloc(NBMAX * 4);
    int*   binnedRow = (int*)alloc((size_t)E * 4);
    unsigned short* binnedCol16 = (unsigned short*)alloc((size_t)E * 2);
    unsigned int* partialDeg = (unsigned int*)alloc((size_t)Md * N * 4);
    unsigned long long* partialAgg = (unsigned long long*)alloc((size_t)Ma * N * 8);
    double* h     = (double*)alloc((size_t)N * 8);
    double* dis   = (double*)alloc((size_t)N * 8);
    double* hd    = (double*)alloc((size_t)N * 8);
    float* score32 = (float*)alloc((size_t)N * 4);
    float* p32    = (float*)alloc((size_t)N * 4);
    float* tg     = (float*)alloc((size_t)N * 4);
    int*   keepI  = (int*)  alloc((size_t)N * 4);
    int*   pos    = (int*)  alloc((size_t)N * 4);
    int nb = (N + SCAN_CHUNK - 1) / SCAN_CHUNK;
    int*   bs     = (int*)  alloc((size_t)nb * 4);
    int*   bo     = (int*)  alloc((size_t)nb * 4);

    // output layout (all float32, concatenated)
    float* o_x     = (float*)d_out;
    float* o_edge  = o_x + (size_t)N * C;
    float* o_keep  = o_edge + 2 * (size_t)E;
    float* o_ekeep = o_keep + N;
    float* o_n1    = o_ekeep + E;
    float* o_n2    = o_n1 + S;
    float* o_sent  = o_n2 + S;

    (void)hipMemsetAsync(binCnt, 0, NBMAX * 4, stream);

    k_h<<<(N * 32 + 255) / 256, 256, 0, stream>>>(x, W, h, N, C);
    k_hist<<<512, 256, 0, stream>>>(ecol, binCnt, E, NB);
    k_off<<<1, 64, 0, stream>>>(binCnt, binOff, binWr, NB);
    int nBatches = (int)(((long)E + 2047) / 2048);
    k_bin<<<nBatches, 256, 0, stream>>>(erow, ecol, binWr, binnedRow, binnedCol16, E, NB);
    k_degb<<<NB * Md, 256, 0, stream>>>(binnedCol16, binOff, partialDeg, N, Md);
    k_dis_hd<<<(N + 255) / 256, 256, 0, stream>>>(partialDeg, h, dis, hd, N, Md);
    k_aggb<<<NB * Ma, 256, 0, stream>>>(binnedRow, binnedCol16, binOff, hd, dis, partialAgg, N, Ma);
    k_score<<<(N + 255) / 256, 256, 0, stream>>>(partialAgg, h, dis, bp, score32, tg, N, Ma);
    k_seg_np<<<(S + 255) / 256, 256, 0, stream>>>(score32, n1, p32, keepI, alphaPtr, N, S);
    k_union<<<(S + 255) / 256, 256, 0, stream>>>(n1, n2, sent, keepI, S);
    k_scanA<<<nb, 256, 0, stream>>>(keepI, bs, N);
    k_scanB<<<1, 256, 0, stream>>>(bs, bo, nb);
    k_scanC<<<nb, 256, 0, stream>>>(keepI, bo, pos, o_keep, N);

    long total4 = (long)N * (C / 4);
    int nxb = (int)((total4 + 255) / 256);
    int neb = (E + 255) / 256;
    int nsb = (S + 255) / 256;
    k_out<<<nxb + neb + nsb, 256, 0, stream>>>(
        (const float4*)x, keepI, tg, o_x, total4,
        erow, ecol, pos, o_edge, o_ekeep, E,
        n1, n2, sent, o_n1, o_n2, o_sent, S, nxb, neb);
}

// Round 8
// 265.071 us; speedup vs baseline: 1.8692x; 1.0606x over previous
//
#include <hip/hip_runtime.h>
#include <math.h>

#define WAVE 64
#define FXSCALE 4398046511104.0   // 2^42
#define WINDOW 7936               // nodes per col-bin (LDS u64[WINDOW] = 63.5 KB)
#define NBMAX 32

typedef float vfloat4 __attribute__((ext_vector_type(4)));

// h[i] = dot(x[i,:], W) in fp64   (one 32-lane half-wave per row, float4 loads)
__global__ void k_h(const float* __restrict__ x, const float* __restrict__ W,
                    double* __restrict__ h, int N, int C) {
    int t = blockIdx.x * blockDim.x + threadIdx.x;
    int row = t >> 5;
    int lane = t & 31;
    if (row >= N) return;
    const float4* xr = (const float4*)(x + (size_t)row * C);
    const float4* w4 = (const float4*)W;
    int C4 = C >> 2;
    double acc = 0.0;
    for (int c = lane; c < C4; c += 32) {
        float4 xv = xr[c];
        float4 wv = w4[c];
        acc += (double)xv.x * (double)wv.x + (double)xv.y * (double)wv.y
             + (double)xv.z * (double)wv.z + (double)xv.w * (double)wv.w;
    }
    #pragma unroll
    for (int o = 16; o > 0; o >>= 1) acc += __shfl_xor(acc, o);
    if (lane == 0) h[row] = acc;
}

// bin histogram: LDS counters, one global atomic per (block,bin)
__global__ void k_hist(const int* __restrict__ ecol, int* __restrict__ binCnt,
                       int E, int NB) {
    __shared__ int cnt[NBMAX];
    int tid = threadIdx.x;
    if (tid < NBMAX) cnt[tid] = 0;
    __syncthreads();
    for (long e = (long)blockIdx.x * blockDim.x + tid; e < E; e += (long)gridDim.x * blockDim.x)
        atomicAdd(&cnt[ecol[e] / WINDOW], 1);
    __syncthreads();
    if (tid < NB && cnt[tid] > 0) atomicAdd(&binCnt[tid], cnt[tid]);
}

// exclusive scan of bins + init write cursors (1 thread)
__global__ void k_off(const int* __restrict__ binCnt, int* __restrict__ binOff,
                      int* __restrict__ binWr, int NB) {
    if (threadIdx.x != 0 || blockIdx.x != 0) return;
    int acc = 0;
    for (int i = 0; i < NB; i++) {
        binOff[i] = acc;
        binWr[i] = acc;
        acc += binCnt[i];
    }
    binOff[NB] = acc;
}

// partition edges by col-window: one batch of 2048 edges per block.
__global__ void k_bin(const int* __restrict__ erow, const int* __restrict__ ecol,
                      int* __restrict__ binWr, int* __restrict__ binnedRow,
                      unsigned short* __restrict__ binnedCol16, int E, int NB) {
    __shared__ int cnt[NBMAX];
    __shared__ int base[NBMAX];
    int tid = threadIdx.x;
    if (tid < NBMAX) cnt[tid] = 0;
    __syncthreads();
    long b0 = (long)blockIdx.x * 2048;
    int bArr[8], rArr[8], rowA[8], colA[8];
    #pragma unroll
    for (int k = 0; k < 8; k++) {
        long e = b0 + (long)k * 256 + tid;
        if (e < E) {
            int c = ecol[e];
            int b = c / WINDOW;
            bArr[k] = b; rowA[k] = erow[e]; colA[k] = c - b * WINDOW;
            rArr[k] = atomicAdd(&cnt[b], 1);
        } else bArr[k] = -1;
    }
    __syncthreads();
    if (tid < NB && cnt[tid] > 0) base[tid] = atomicAdd(&binWr[tid], cnt[tid]);
    __syncthreads();
    #pragma unroll
    for (int k = 0; k < 8; k++) {
        if (bArr[k] >= 0) {
            int idx = base[bArr[k]] + rArr[k];
            binnedRow[idx] = rowA[k];
            binnedCol16[idx] = (unsigned short)colA[k];
        }
    }
}

// per-(bin,m) LDS degree histogram -> coalesced partial store (no global atomics)
__global__ void k_degb(const unsigned short* __restrict__ binnedCol16,
                       const int* __restrict__ binOff,
                       unsigned int* __restrict__ partialDeg, int N, int Md) {
    __shared__ unsigned int cnt[WINDOW];
    int bin = blockIdx.x / Md, m = blockIdx.x % Md;
    int tid = threadIdx.x;
    for (int i = tid; i < WINDOW; i += blockDim.x) cnt[i] = 0;
    __syncthreads();
    int st = binOff[bin], en = binOff[bin + 1];
    for (int idx = st + m * (int)blockDim.x + tid; idx < en; idx += Md * (int)blockDim.x)
        atomicAdd(&cnt[binnedCol16[idx]], 1u);
    __syncthreads();
    int wb = bin * WINDOW;
    for (int i = tid; i < WINDOW && wb + i < N; i += blockDim.x)
        partialDeg[(size_t)m * N + wb + i] = cnt[i];
}

// dis = 1/sqrt(deg+1); hd = h*dis
__global__ void k_dis_hd(const unsigned int* __restrict__ partialDeg,
                         const double* __restrict__ h,
                         double* __restrict__ dis, double* __restrict__ hd,
                         int N, int Md) {
    int i = blockIdx.x * blockDim.x + threadIdx.x;
    if (i >= N) return;
    unsigned int dsum = 0;
    for (int m = 0; m < Md; m++) dsum += partialDeg[(size_t)m * N + i];
    double d = 1.0 / sqrt((double)dsum + 1.0);
    dis[i] = d;
    hd[i] = h[i] * d;
}

// per-(bin,m) LDS u64 fixed-point accumulate -> coalesced partial store.
__global__ void k_aggb(const int* __restrict__ binnedRow,
                       const unsigned short* __restrict__ binnedCol16,
                       const int* __restrict__ binOff,
                       const double* __restrict__ hd, const double* __restrict__ dis,
                       unsigned long long* __restrict__ partialAgg, int N, int Ma) {
    __shared__ unsigned long long acc[WINDOW];   // 63.5 KB
    int bin = blockIdx.x / Ma, m = blockIdx.x % Ma;
    int tid = threadIdx.x;
    for (int i = tid; i < WINDOW; i += blockDim.x) acc[i] = 0ULL;
    __syncthreads();
    int st = binOff[bin], en = binOff[bin + 1];
    int wb = bin * WINDOW;
    for (int idx = st + m * (int)blockDim.x + tid; idx < en; idx += Ma * (int)blockDim.x) {
        int r = binnedRow[idx];
        int c16 = binnedCol16[idx];
        long long q = __double2ll_rn(hd[r] * dis[wb + c16] * FXSCALE);
        atomicAdd(&acc[c16], (unsigned long long)q);
    }
    __syncthreads();
    for (int i = tid; i < WINDOW && wb + i < N; i += blockDim.x)
        partialAgg[(size_t)m * N + wb + i] = acc[i];
}

// score (fp64, rounded to fp32) ; tg = tanh(score) fp32
__global__ void k_score(const unsigned long long* __restrict__ partialAgg,
                        const double* __restrict__ h, const double* __restrict__ dis,
                        const float* __restrict__ bptr,
                        float* __restrict__ score32, float* __restrict__ tg,
                        int N, int Ma) {
    int i = blockIdx.x * blockDim.x + threadIdx.x;
    if (i >= N) return;
    long long acc = 0;
    for (int m = 0; m < Ma; m++) acc += (long long)partialAgg[(size_t)m * N + i];
    double agg = (double)acc / FXSCALE;
    double d = dis[i];
    double sc = (agg + h[i] * (d * d)) + (double)bptr[0];
    score32[i] = (float)sc;
    tg[i] = (float)tanh(sc);
}

// One THREAD per segment — keep numerics byte-identical to passing rounds.
// Union of special nodes folded in (indices lie inside this thread's segment).
__global__ void k_seg_np(const float* __restrict__ score32, const int* __restrict__ starts,
                         float* __restrict__ p32, int* __restrict__ keepI,
                         const int* __restrict__ alphaPtr,
                         const int* __restrict__ n1, const int* __restrict__ n2,
                         const int* __restrict__ sent, int N, int S) {
    int g = blockIdx.x * blockDim.x + threadIdx.x;
    if (g >= S) return;
    int st = starts[g];
    int en = (g == S - 1) ? N : starts[g + 1];
    if (en <= st) return;

    int ai = alphaPtr[0];
    float alpha = (ai >= 0 && ai < 1000000) ? (float)ai : __int_as_float(ai);

    float m = -3.402823466e38f;
    for (int i = st; i < en; i++) m = fmaxf(m, score32[i]);

    float Z = 0.0f;
    for (int i = st; i < en; i++) {
        float dm = __fsub_rn(score32[i], m);
        float e = (float)exp((double)dm);   // correctly-rounded fp32 exp
        p32[i] = e;
        Z = __fadd_rn(Z, e);
    }

    float sp = 0.0f, sq = 0.0f, pm = -3.402823466e38f;
    for (int i = st; i < en; i++) {
        float p = __fdiv_rn(p32[i], Z);
        p32[i] = p;
        sp = __fadd_rn(sp, p);
        sq = __fadd_rn(sq, __fmul_rn(p, p));
        pm = fmaxf(pm, p);
    }

    float cnt_ = (float)(en - st);
    float mean = __fdiv_rn(sp, cnt_);
    float var = __fsub_rn(__fdiv_rn(sq, cnt_), __fmul_rn(mean, mean));
    float sd = sqrtf(fmaxf(var, 0.0f));
    float cutoff = __fsub_rn(pm, __fmul_rn(alpha, sd));

    for (int i = st; i < en; i++) keepI[i] = (p32[i] >= cutoff) ? 1 : 0;

    // union with special nodes (all within [st,en) for this dataset)
    keepI[n1[g]] = 1;
    keepI[n2[g]] = 1;
    keepI[sent[g]] = 1;
}

#define SCAN_CHUNK 2048  // 256 threads * 8

__global__ void k_scanA(const int* __restrict__ keepI, int* __restrict__ bs, int N) {
    int tid = threadIdx.x;
    long base = (long)blockIdx.x * SCAN_CHUNK + (long)tid * 8;
    int s = 0;
    #pragma unroll
    for (int k = 0; k < 8; k++) { long i = base + k; if (i < N) s += keepI[i]; }
    __shared__ int sm[256];
    sm[tid] = s; __syncthreads();
    for (int off = 128; off > 0; off >>= 1) {
        if (tid < off) sm[tid] += sm[tid + off];
        __syncthreads();
    }
    if (tid == 0) bs[blockIdx.x] = sm[0];
}

__global__ void k_scanB(const int* __restrict__ bs, int* __restrict__ bo, int nb) {
    __shared__ int sm[256];
    __shared__ int carrySh;
    int tid = threadIdx.x;
    if (tid == 0) carrySh = 0;
    __syncthreads();
    for (int base = 0; base < nb; base += 256) {
        int i = base + tid;
        int v = (i < nb) ? bs[i] : 0;
        sm[tid] = v; __syncthreads();
        for (int off = 1; off < 256; off <<= 1) {
            int t = (tid >= off) ? sm[tid - off] : 0;
            __syncthreads();
            sm[tid] += t;
            __syncthreads();
        }
        int incl = sm[tid];
        int total = sm[255];
        int carry = carrySh;
        if (i < nb) bo[i] = carry + incl - v;
        __syncthreads();
        if (tid == 0) carrySh = carry + total;
        __syncthreads();
    }
}

// final scan: posTag = keep ? pos : -1 ; gate = keep ? tanh : 0 ; o_keep
__global__ void k_scanC(const int* __restrict__ keepI, const int* __restrict__ bo,
                        const float* __restrict__ tg,
                        int* __restrict__ posTag, float* __restrict__ gate,
                        float* __restrict__ o_keep, int N) {
    int tid = threadIdx.x;
    long base = (long)blockIdx.x * SCAN_CHUNK + (long)tid * 8;
    int v[8];
    int th = 0;
    #pragma unroll
    for (int k = 0; k < 8; k++) {
        long i = base + k;
        v[k] = (i < N) ? keepI[i] : 0;
        th += v[k];
    }
    __shared__ int sm[256];
    sm[tid] = th; __syncthreads();
    for (int off = 1; off < 256; off <<= 1) {
        int t = (tid >= off) ? sm[tid - off] : 0;
        __syncthreads();
        sm[tid] += t;
        __syncthreads();
    }
    int excl = sm[tid] - th;
    int run = bo[blockIdx.x] + excl;
    #pragma unroll
    for (int k = 0; k < 8; k++) {
        long i = base + k;
        if (i < N) {
            posTag[i] = v[k] ? (run + v[k] - 1) : -1;
            gate[i] = v[k] ? tg[i] : 0.0f;
            o_keep[i] = v[k] ? 1.0f : 0.0f;
            run += v[k];
        }
    }
}

// fused outputs: [0,nxb) x_out float4s; [nxb,nxb+neb4) edges x4; rest nodes
__global__ void k_out(const float4* __restrict__ x4, const float* __restrict__ gate,
                      float* __restrict__ o_x, long total4,
                      const int* __restrict__ erow, const int* __restrict__ ecol,
                      const int* __restrict__ posTag,
                      float* __restrict__ o_edge, float* __restrict__ o_ekeep, int E,
                      const int* __restrict__ n1, const int* __restrict__ n2,
                      const int* __restrict__ sent,
                      float* __restrict__ o_n1, float* __restrict__ o_n2,
                      float* __restrict__ o_sent, int S,
                      int nxb, int neb4) {
    int b = blockIdx.x;
    if (b < nxb) {
        long idx = (long)b * blockDim.x + threadIdx.x;
        if (idx >= total4) return;
        int row = (int)(idx >> 5);   // C/4 = 32 float4 per row
        float g = gate[row];
        float4 v = x4[idx];
        vfloat4 r = { v.x * g, v.y * g, v.z * g, v.w * g };
        __builtin_nontemporal_store(r, (vfloat4*)o_x + idx);
    } else if (b < nxb + neb4) {
        long e0 = ((long)(b - nxb) * blockDim.x + threadIdx.x) * 4;
        if (e0 >= E) return;
        if (e0 + 3 < E) {
            int4 r4 = *(const int4*)(erow + e0);
            int4 c4 = *(const int4*)(ecol + e0);
            vfloat4 oer, oec, ok;
            #pragma unroll
            for (int k = 0; k < 4; k++) {
                int r = (&r4.x)[k], c = (&c4.x)[k];
                int pr = posTag[r], pc = posTag[c];
                bool ek = (pr >= 0) && (pc >= 0);
                oer[k] = ek ? (float)pr : -1.0f;
                oec[k] = ek ? (float)pc : -1.0f;
                ok[k]  = ek ? 1.0f : 0.0f;
            }
            __builtin_nontemporal_store(oer, (vfloat4*)(o_edge + e0));
            __builtin_nontemporal_store(oec, (vfloat4*)(o_edge + (size_t)E + e0));
            __builtin_nontemporal_store(ok,  (vfloat4*)(o_ekeep + e0));
        } else {
            for (long e = e0; e < E; e++) {
                int r = erow[e], c = ecol[e];
                int pr = posTag[r], pc = posTag[c];
                bool ek = (pr >= 0) && (pc >= 0);
                o_edge[e] = ek ? (float)pr : -1.0f;
                o_edge[(size_t)E + e] = ek ? (float)pc : -1.0f;
                o_ekeep[e] = ek ? 1.0f : 0.0f;
            }
        }
    } else {
        int i = (b - nxb - neb4) * blockDim.x + threadIdx.x;
        if (i >= S) return;
        o_n1[i] = (float)posTag[n1[i]];
        o_n2[i] = (float)posTag[n2[i]];
        o_sent[i] = (float)posTag[sent[i]];
    }
}

extern "C" void kernel_launch(void* const* d_in, const int* in_sizes, int n_in,
                              void* d_out, int out_size, void* d_ws, size_t ws_size,
                              hipStream_t stream) {
    const float* x    = (const float*)d_in[0];
    const int*   eidx = (const int*)d_in[1];
    const int*   n1   = (const int*)d_in[2];
    const int*   n2   = (const int*)d_in[3];
    const int*   sent = (const int*)d_in[4];
    const float* W    = (const float*)d_in[5];
    const float* bp   = (const float*)d_in[6];
    const int*   alphaPtr = (const int*)d_in[7];

    int C = in_sizes[5];                 // W is [C,1]
    int N = in_sizes[0] / C;
    int E = in_sizes[1] / 2;
    int S = in_sizes[2];

    const int* erow = eidx;
    const int* ecol = eidx + E;

    int NB = (N + WINDOW - 1) / WINDOW;  // 26 for N=200000
    const int Md = 8, Ma = 8;

    // workspace layout
    char* ws = (char*)d_ws;
    size_t off = 0;
    auto alloc = [&](size_t bytes) { void* p = ws + off; off += (bytes + 255) & ~(size_t)255; return p; };
    int*   binCnt = (int*)  alloc(NBMAX * 4);          // zeroed
    int*   binOff = (int*)  alloc((NBMAX + 1) * 4);
    int*   binWr  = (int*)  alloc(NBMAX * 4);
    int*   binnedRow = (int*)alloc((size_t)E * 4);
    unsigned short* binnedCol16 = (unsigned short*)alloc((size_t)E * 2);
    unsigned int* partialDeg = (unsigned int*)alloc((size_t)Md * N * 4);
    unsigned long long* partialAgg = (unsigned long long*)alloc((size_t)Ma * N * 8);
    double* h     = (double*)alloc((size_t)N * 8);
    double* dis   = (double*)alloc((size_t)N * 8);
    double* hd    = (double*)alloc((size_t)N * 8);
    float* score32 = (float*)alloc((size_t)N * 4);
    float* p32    = (float*)alloc((size_t)N * 4);
    float* tg     = (float*)alloc((size_t)N * 4);
    int*   keepI  = (int*)  alloc((size_t)N * 4);
    int*   posTag = (int*)  alloc((size_t)N * 4);
    float* gate   = (float*)alloc((size_t)N * 4);
    int nb = (N + SCAN_CHUNK - 1) / SCAN_CHUNK;
    int*   bs     = (int*)  alloc((size_t)nb * 4);
    int*   bo     = (int*)  alloc((size_t)nb * 4);

    // output layout (all float32, concatenated)
    float* o_x     = (float*)d_out;
    float* o_edge  = o_x + (size_t)N * C;
    float* o_keep  = o_edge + 2 * (size_t)E;
    float* o_ekeep = o_keep + N;
    float* o_n1    = o_ekeep + E;
    float* o_n2    = o_n1 + S;
    float* o_sent  = o_n2 + S;

    (void)hipMemsetAsync(binCnt, 0, NBMAX * 4, stream);

    k_h<<<(N * 32 + 255) / 256, 256, 0, stream>>>(x, W, h, N, C);
    k_hist<<<512, 256, 0, stream>>>(ecol, binCnt, E, NB);
    k_off<<<1, 64, 0, stream>>>(binCnt, binOff, binWr, NB);
    int nBatches = (int)(((long)E + 2047) / 2048);
    k_bin<<<nBatches, 256, 0, stream>>>(erow, ecol, binWr, binnedRow, binnedCol16, E, NB);
    k_degb<<<NB * Md, 256, 0, stream>>>(binnedCol16, binOff, partialDeg, N, Md);
    k_dis_hd<<<(N + 255) / 256, 256, 0, stream>>>(partialDeg, h, dis, hd, N, Md);
    k_aggb<<<NB * Ma, 256, 0, stream>>>(binnedRow, binnedCol16, binOff, hd, dis, partialAgg, N, Ma);
    k_score<<<(N + 255) / 256, 256, 0, stream>>>(partialAgg, h, dis, bp, score32, tg, N, Ma);
    k_seg_np<<<(S + 255) / 256, 256, 0, stream>>>(score32, n1, p32, keepI, alphaPtr, n1, n2, sent, N, S);
    k_scanA<<<nb, 256, 0, stream>>>(keepI, bs, N);
    k_scanB<<<1, 256, 0, stream>>>(bs, bo, nb);
    k_scanC<<<nb, 256, 0, stream>>>(keepI, bo, tg, posTag, gate, o_keep, N);

    long total4 = (long)N * (C / 4);
    int nxb = (int)((total4 + 255) / 256);
    long e4 = (E + 3) / 4;
    int neb4 = (int)((e4 + 255) / 256);
    int nsb = (S + 255) / 256;
    k_out<<<nxb + neb4 + nsb, 256, 0, stream>>>(
        (const float4*)x, gate, o_x, total4,
        erow, ecol, posTag, o_edge, o_ekeep, E,
        n1, n2, sent, o_n1, o_n2, o_sent, S, nxb, neb4);
}

// Round 9
// 251.580 us; speedup vs baseline: 1.9695x; 1.0536x over previous
//
#include <hip/hip_runtime.h>
#include <math.h>

#define WAVE 64
#define FXSCALE 4398046511104.0   // 2^42
#define WINDOW 7936               // nodes per col-bin (LDS u64[WINDOW] = 63.5 KB)
#define NBMAX 32
#define BINB 2048

typedef float vfloat4 __attribute__((ext_vector_type(4)));

// fused: blocks [0,nhb) compute h = x@W (fp64, half-wave per row);
// blocks [nhb, nhb+512) build the col-window histogram.
__global__ void k_h_hist(const float* __restrict__ x, const float* __restrict__ W,
                         double* __restrict__ h,
                         const int* __restrict__ ecol, int* __restrict__ binCnt,
                         int N, int C, int E, int NB, int nhb) {
    int b = blockIdx.x;
    if (b < nhb) {
        int t = b * 256 + threadIdx.x;
        int row = t >> 5;
        int lane = t & 31;
        if (row >= N) return;
        const float4* xr = (const float4*)(x + (size_t)row * C);
        const float4* w4 = (const float4*)W;
        int C4 = C >> 2;
        double acc = 0.0;
        for (int c = lane; c < C4; c += 32) {
            float4 xv = xr[c];
            float4 wv = w4[c];
            acc += (double)xv.x * (double)wv.x + (double)xv.y * (double)wv.y
                 + (double)xv.z * (double)wv.z + (double)xv.w * (double)wv.w;
        }
        #pragma unroll
        for (int o = 16; o > 0; o >>= 1) acc += __shfl_xor(acc, o);
        if (lane == 0) h[row] = acc;
    } else {
        __shared__ int cnt[NBMAX];
        int tid = threadIdx.x;
        if (tid < NBMAX) cnt[tid] = 0;
        __syncthreads();
        int hb = b - nhb;
        for (long e = (long)hb * 256 + tid; e < E; e += 512L * 256)
            atomicAdd(&cnt[ecol[e] / WINDOW], 1);
        __syncthreads();
        if (tid < NB && cnt[tid] > 0) atomicAdd(&binCnt[tid], cnt[tid]);
    }
}

// exclusive scan of bins + init write cursors (1 thread)
__global__ void k_off(const int* __restrict__ binCnt, int* __restrict__ binOff,
                      int* __restrict__ binWr, int NB) {
    if (threadIdx.x != 0 || blockIdx.x != 0) return;
    int acc = 0;
    for (int i = 0; i < NB; i++) {
        binOff[i] = acc;
        binWr[i] = acc;
        acc += binCnt[i];
    }
    binOff[NB] = acc;
}

// partition edges by col-window: block-local LDS counting sort -> coalesced copy-out.
__global__ void k_bin(const int* __restrict__ erow, const int* __restrict__ ecol,
                      int* __restrict__ binWr, int* __restrict__ binnedRow,
                      unsigned short* __restrict__ binnedCol16, int E, int NB) {
    __shared__ int cnt[NBMAX];
    __shared__ int lbase[NBMAX];
    __shared__ int gbase[NBMAX];
    __shared__ int lrow[BINB];
    __shared__ unsigned short lcol[BINB];
    __shared__ unsigned char lbin[BINB];
    int tid = threadIdx.x;
    if (tid < NBMAX) cnt[tid] = 0;
    __syncthreads();
    long b0 = (long)blockIdx.x * BINB;
    int n = (int)((E - b0) < (long)BINB ? (E - b0) : (long)BINB);
    int bA[8], rkA[8], rwA[8];
    unsigned short clA[8];
    #pragma unroll
    for (int k = 0; k < 8; k++) bA[k] = -1;
    int base_i = tid * 8;
    if (base_i + 8 <= n) {
        long e = b0 + base_i;
        int4 r0 = *(const int4*)(erow + e), r1 = *(const int4*)(erow + e + 4);
        int4 c0 = *(const int4*)(ecol + e), c1 = *(const int4*)(ecol + e + 4);
        int rr[8] = {r0.x, r0.y, r0.z, r0.w, r1.x, r1.y, r1.z, r1.w};
        int cc[8] = {c0.x, c0.y, c0.z, c0.w, c1.x, c1.y, c1.z, c1.w};
        #pragma unroll
        for (int k = 0; k < 8; k++) {
            int c = cc[k];
            int bb = c / WINDOW;
            bA[k] = bb; rwA[k] = rr[k]; clA[k] = (unsigned short)(c - bb * WINDOW);
            rkA[k] = atomicAdd(&cnt[bb], 1);
        }
    } else {
        for (int k = 0; k < 8; k++) {
            int i = base_i + k;
            if (i < n) {
                long e = b0 + i;
                int c = ecol[e];
                int bb = c / WINDOW;
                bA[k] = bb; rwA[k] = erow[e]; clA[k] = (unsigned short)(c - bb * WINDOW);
                rkA[k] = atomicAdd(&cnt[bb], 1);
            }
        }
    }
    __syncthreads();
    if (tid == 0) {
        int acc = 0;
        for (int i = 0; i < NB; i++) { lbase[i] = acc; acc += cnt[i]; }
    }
    __syncthreads();
    if (tid < NB && cnt[tid] > 0) gbase[tid] = atomicAdd(&binWr[tid], cnt[tid]);
    __syncthreads();
    #pragma unroll
    for (int k = 0; k < 8; k++) {
        if (bA[k] >= 0) {
            int l = lbase[bA[k]] + rkA[k];
            lrow[l] = rwA[k];
            lcol[l] = clA[k];
            lbin[l] = (unsigned char)bA[k];
        }
    }
    __syncthreads();
    for (int l = tid; l < n; l += 256) {
        int bb = lbin[l];
        int g = gbase[bb] + (l - lbase[bb]);
        binnedRow[g] = lrow[l];
        binnedCol16[g] = lcol[l];
    }
}

// per-(bin,m) LDS degree histogram -> coalesced partial store (no global atomics)
__global__ void k_degb(const unsigned short* __restrict__ binnedCol16,
                       const int* __restrict__ binOff,
                       unsigned int* __restrict__ partialDeg, int N, int Md) {
    __shared__ unsigned int cnt[WINDOW];
    int bin = blockIdx.x / Md, m = blockIdx.x % Md;
    int tid = threadIdx.x;
    for (int i = tid; i < WINDOW; i += blockDim.x) cnt[i] = 0;
    __syncthreads();
    int st = binOff[bin], en = binOff[bin + 1];
    for (int idx = st + m * (int)blockDim.x + tid; idx < en; idx += Md * (int)blockDim.x)
        atomicAdd(&cnt[binnedCol16[idx]], 1u);
    __syncthreads();
    int wb = bin * WINDOW;
    for (int i = tid; i < WINDOW && wb + i < N; i += blockDim.x)
        partialDeg[(size_t)m * N + wb + i] = cnt[i];
}

// dis = 1/sqrt(deg+1); hd = h*dis
__global__ void k_dis_hd(const unsigned int* __restrict__ partialDeg,
                         const double* __restrict__ h,
                         double* __restrict__ dis, double* __restrict__ hd,
                         int N, int Md) {
    int i = blockIdx.x * blockDim.x + threadIdx.x;
    if (i >= N) return;
    unsigned int dsum = 0;
    for (int m = 0; m < Md; m++) dsum += partialDeg[(size_t)m * N + i];
    double d = 1.0 / sqrt((double)dsum + 1.0);
    dis[i] = d;
    hd[i] = h[i] * d;
}

// per-(bin,m) LDS u64 fixed-point accumulate -> coalesced partial store.
__global__ void k_aggb(const int* __restrict__ binnedRow,
                       const unsigned short* __restrict__ binnedCol16,
                       const int* __restrict__ binOff,
                       const double* __restrict__ hd, const double* __restrict__ dis,
                       unsigned long long* __restrict__ partialAgg, int N, int Ma) {
    __shared__ unsigned long long acc[WINDOW];   // 63.5 KB
    int bin = blockIdx.x / Ma, m = blockIdx.x % Ma;
    int tid = threadIdx.x;
    for (int i = tid; i < WINDOW; i += blockDim.x) acc[i] = 0ULL;
    __syncthreads();
    int st = binOff[bin], en = binOff[bin + 1];
    int wb = bin * WINDOW;
    for (int idx = st + m * (int)blockDim.x + tid; idx < en; idx += Ma * (int)blockDim.x) {
        int r = binnedRow[idx];
        int c16 = binnedCol16[idx];
        long long q = __double2ll_rn(hd[r] * dis[wb + c16] * FXSCALE);
        atomicAdd(&acc[c16], (unsigned long long)q);
    }
    __syncthreads();
    for (int i = tid; i < WINDOW && wb + i < N; i += blockDim.x)
        partialAgg[(size_t)m * N + wb + i] = acc[i];
}

// score (fp64, rounded to fp32) ; tg = tanh(score) fp32
__global__ void k_score(const unsigned long long* __restrict__ partialAgg,
                        const double* __restrict__ h, const double* __restrict__ dis,
                        const float* __restrict__ bptr,
                        float* __restrict__ score32, float* __restrict__ tg,
                        int N, int Ma) {
    int i = blockIdx.x * blockDim.x + threadIdx.x;
    if (i >= N) return;
    long long acc = 0;
    for (int m = 0; m < Ma; m++) acc += (long long)partialAgg[(size_t)m * N + i];
    double agg = (double)acc / FXSCALE;
    double d = dis[i];
    double sc = (agg + h[i] * (d * d)) + (double)bptr[0];
    score32[i] = (float)sc;
    tg[i] = (float)tanh(sc);
}

// One THREAD per segment — keep numerics byte-identical to passing rounds.
__global__ void k_seg_np(const float* __restrict__ score32, const int* __restrict__ starts,
                         float* __restrict__ p32, int* __restrict__ keepI,
                         const int* __restrict__ alphaPtr,
                         const int* __restrict__ n1, const int* __restrict__ n2,
                         const int* __restrict__ sent, int N, int S) {
    int g = blockIdx.x * blockDim.x + threadIdx.x;
    if (g >= S) return;
    int st = starts[g];
    int en = (g == S - 1) ? N : starts[g + 1];
    if (en <= st) return;

    int ai = alphaPtr[0];
    float alpha = (ai >= 0 && ai < 1000000) ? (float)ai : __int_as_float(ai);

    float m = -3.402823466e38f;
    for (int i = st; i < en; i++) m = fmaxf(m, score32[i]);

    float Z = 0.0f;
    for (int i = st; i < en; i++) {
        float dm = __fsub_rn(score32[i], m);
        float e = (float)exp((double)dm);   // correctly-rounded fp32 exp
        p32[i] = e;
        Z = __fadd_rn(Z, e);
    }

    float sp = 0.0f, sq = 0.0f, pm = -3.402823466e38f;
    for (int i = st; i < en; i++) {
        float p = __fdiv_rn(p32[i], Z);
        p32[i] = p;
        sp = __fadd_rn(sp, p);
        sq = __fadd_rn(sq, __fmul_rn(p, p));
        pm = fmaxf(pm, p);
    }

    float cnt_ = (float)(en - st);
    float mean = __fdiv_rn(sp, cnt_);
    float var = __fsub_rn(__fdiv_rn(sq, cnt_), __fmul_rn(mean, mean));
    float sd = sqrtf(fmaxf(var, 0.0f));
    float cutoff = __fsub_rn(pm, __fmul_rn(alpha, sd));

    for (int i = st; i < en; i++) keepI[i] = (p32[i] >= cutoff) ? 1 : 0;

    // union with special nodes (all within [st,en) for this dataset)
    keepI[n1[g]] = 1;
    keepI[n2[g]] = 1;
    keepI[sent[g]] = 1;
}

#define SCAN_CHUNK 2048  // 256 threads * 8

__global__ void k_scanA(const int* __restrict__ keepI, int* __restrict__ bs, int N) {
    int tid = threadIdx.x;
    long base = (long)blockIdx.x * SCAN_CHUNK + (long)tid * 8;
    int s = 0;
    #pragma unroll
    for (int k = 0; k < 8; k++) { long i = base + k; if (i < N) s += keepI[i]; }
    __shared__ int sm[256];
    sm[tid] = s; __syncthreads();
    for (int off = 128; off > 0; off >>= 1) {
        if (tid < off) sm[tid] += sm[tid + off];
        __syncthreads();
    }
    if (tid == 0) bs[blockIdx.x] = sm[0];
}

__global__ void k_scanB(const int* __restrict__ bs, int* __restrict__ bo, int nb) {
    __shared__ int sm[256];
    __shared__ int carrySh;
    int tid = threadIdx.x;
    if (tid == 0) carrySh = 0;
    __syncthreads();
    for (int base = 0; base < nb; base += 256) {
        int i = base + tid;
        int v = (i < nb) ? bs[i] : 0;
        sm[tid] = v; __syncthreads();
        for (int off = 1; off < 256; off <<= 1) {
            int t = (tid >= off) ? sm[tid - off] : 0;
            __syncthreads();
            sm[tid] += t;
            __syncthreads();
        }
        int incl = sm[tid];
        int total = sm[255];
        int carry = carrySh;
        if (i < nb) bo[i] = carry + incl - v;
        __syncthreads();
        if (tid == 0) carrySh = carry + total;
        __syncthreads();
    }
}

// final scan: posF = keep ? (float)pos : -1 ; gate = keep ? tanh : 0 ; o_keep
__global__ void k_scanC(const int* __restrict__ keepI, const int* __restrict__ bo,
                        const float* __restrict__ tg,
                        float* __restrict__ posF, float* __restrict__ gate,
                        float* __restrict__ o_keep, int N) {
    int tid = threadIdx.x;
    long base = (long)blockIdx.x * SCAN_CHUNK + (long)tid * 8;
    int v[8];
    int th = 0;
    #pragma unroll
    for (int k = 0; k < 8; k++) {
        long i = base + k;
        v[k] = (i < N) ? keepI[i] : 0;
        th += v[k];
    }
    __shared__ int sm[256];
    sm[tid] = th; __syncthreads();
    for (int off = 1; off < 256; off <<= 1) {
        int t = (tid >= off) ? sm[tid - off] : 0;
        __syncthreads();
        sm[tid] += t;
        __syncthreads();
    }
    int excl = sm[tid] - th;
    int run = bo[blockIdx.x] + excl;
    #pragma unroll
    for (int k = 0; k < 8; k++) {
        long i = base + k;
        if (i < N) {
            posF[i] = v[k] ? (float)(run + v[k] - 1) : -1.0f;
            gate[i] = v[k] ? tg[i] : 0.0f;
            o_keep[i] = v[k] ? 1.0f : 0.0f;
            run += v[k];
        }
    }
}

// fused outputs: [0,nxb) x_out float4s; [nxb,nxb+neb4) edges x4; rest nodes
__global__ void k_out(const float4* __restrict__ x4, const float* __restrict__ gate,
                      float* __restrict__ o_x, long total4,
                      const int* __restrict__ erow, const int* __restrict__ ecol,
                      const float* __restrict__ posF,
                      float* __restrict__ o_edge, float* __restrict__ o_ekeep, int E,
                      const int* __restrict__ n1, const int* __restrict__ n2,
                      const int* __restrict__ sent,
                      float* __restrict__ o_n1, float* __restrict__ o_n2,
                      float* __restrict__ o_sent, int S,
                      int nxb, int neb4) {
    int b = blockIdx.x;
    if (b < nxb) {
        long idx = (long)b * blockDim.x + threadIdx.x;
        if (idx >= total4) return;
        int row = (int)(idx >> 5);   // C/4 = 32 float4 per row
        float g = gate[row];
        float4 v = x4[idx];
        vfloat4 r = { v.x * g, v.y * g, v.z * g, v.w * g };
        __builtin_nontemporal_store(r, (vfloat4*)o_x + idx);
    } else if (b < nxb + neb4) {
        long e0 = ((long)(b - nxb) * blockDim.x + threadIdx.x) * 4;
        if (e0 >= E) return;
        if (e0 + 3 < E) {
            int4 r4 = *(const int4*)(erow + e0);
            int4 c4 = *(const int4*)(ecol + e0);
            vfloat4 oer, oec, ok;
            #pragma unroll
            for (int k = 0; k < 4; k++) {
                int r = (&r4.x)[k], c = (&c4.x)[k];
                float pr = posF[r], pc = posF[c];
                bool ek = (pr >= 0.0f) && (pc >= 0.0f);
                oer[k] = ek ? pr : -1.0f;
                oec[k] = ek ? pc : -1.0f;
                ok[k]  = ek ? 1.0f : 0.0f;
            }
            __builtin_nontemporal_store(oer, (vfloat4*)(o_edge + e0));
            __builtin_nontemporal_store(oec, (vfloat4*)(o_edge + (size_t)E + e0));
            __builtin_nontemporal_store(ok,  (vfloat4*)(o_ekeep + e0));
        } else {
            for (long e = e0; e < E; e++) {
                int r = erow[e], c = ecol[e];
                float pr = posF[r], pc = posF[c];
                bool ek = (pr >= 0.0f) && (pc >= 0.0f);
                o_edge[e] = ek ? pr : -1.0f;
                o_edge[(size_t)E + e] = ek ? pc : -1.0f;
                o_ekeep[e] = ek ? 1.0f : 0.0f;
            }
        }
    } else {
        int i = (b - nxb - neb4) * blockDim.x + threadIdx.x;
        if (i >= S) return;
        o_n1[i] = posF[n1[i]];
        o_n2[i] = posF[n2[i]];
        o_sent[i] = posF[sent[i]];
    }
}

extern "C" void kernel_launch(void* const* d_in, const int* in_sizes, int n_in,
                              void* d_out, int out_size, void* d_ws, size_t ws_size,
                              hipStream_t stream) {
    const float* x    = (const float*)d_in[0];
    const int*   eidx = (const int*)d_in[1];
    const int*   n1   = (const int*)d_in[2];
    const int*   n2   = (const int*)d_in[3];
    const int*   sent = (const int*)d_in[4];
    const float* W    = (const float*)d_in[5];
    const float* bp   = (const float*)d_in[6];
    const int*   alphaPtr = (const int*)d_in[7];

    int C = in_sizes[5];                 // W is [C,1]
    int N = in_sizes[0] / C;
    int E = in_sizes[1] / 2;
    int S = in_sizes[2];

    const int* erow = eidx;
    const int* ecol = eidx + E;

    int NB = (N + WINDOW - 1) / WINDOW;  // 26 for N=200000
    const int Md = 8, Ma = 8;

    // workspace layout
    char* ws = (char*)d_ws;
    size_t off = 0;
    auto alloc = [&](size_t bytes) { void* p = ws + off; off += (bytes + 255) & ~(size_t)255; return p; };
    int*   binCnt = (int*)  alloc(NBMAX * 4);          // zeroed
    int*   binOff = (int*)  alloc((NBMAX + 1) * 4);
    int*   binWr  = (int*)  alloc(NBMAX * 4);
    int*   binnedRow = (int*)alloc((size_t)E * 4);
    unsigned short* binnedCol16 = (unsigned short*)alloc((size_t)E * 2);
    unsigned int* partialDeg = (unsigned int*)alloc((size_t)Md * N * 4);
    unsigned long long* partialAgg = (unsigned long long*)alloc((size_t)Ma * N * 8);
    double* h     = (double*)alloc((size_t)N * 8);
    double* dis   = (double*)alloc((size_t)N * 8);
    double* hd    = (double*)alloc((size_t)N * 8);
    float* score32 = (float*)alloc((size_t)N * 4);
    float* p32    = (float*)alloc((size_t)N * 4);
    float* tg     = (float*)alloc((size_t)N * 4);
    int*   keepI  = (int*)  alloc((size_t)N * 4);
    float* posF   = (float*)alloc((size_t)N * 4);
    float* gate   = (float*)alloc((size_t)N * 4);
    int nb = (N + SCAN_CHUNK - 1) / SCAN_CHUNK;
    int*   bs     = (int*)  alloc((size_t)nb * 4);
    int*   bo     = (int*)  alloc((size_t)nb * 4);

    // output layout (all float32, concatenated)
    float* o_x     = (float*)d_out;
    float* o_edge  = o_x + (size_t)N * C;
    float* o_keep  = o_edge + 2 * (size_t)E;
    float* o_ekeep = o_keep + N;
    float* o_n1    = o_ekeep + E;
    float* o_n2    = o_n1 + S;
    float* o_sent  = o_n2 + S;

    (void)hipMemsetAsync(binCnt, 0, NBMAX * 4, stream);

    int nhb = (N * 32 + 255) / 256;
    k_h_hist<<<nhb + 512, 256, 0, stream>>>(x, W, h, ecol, binCnt, N, C, E, NB, nhb);
    k_off<<<1, 64, 0, stream>>>(binCnt, binOff, binWr, NB);
    int nBatches = (int)(((long)E + BINB - 1) / BINB);
    k_bin<<<nBatches, 256, 0, stream>>>(erow, ecol, binWr, binnedRow, binnedCol16, E, NB);
    k_degb<<<NB * Md, 256, 0, stream>>>(binnedCol16, binOff, partialDeg, N, Md);
    k_dis_hd<<<(N + 255) / 256, 256, 0, stream>>>(partialDeg, h, dis, hd, N, Md);
    k_aggb<<<NB * Ma, 256, 0, stream>>>(binnedRow, binnedCol16, binOff, hd, dis, partialAgg, N, Ma);
    k_score<<<(N + 255) / 256, 256, 0, stream>>>(partialAgg, h, dis, bp, score32, tg, N, Ma);
    k_seg_np<<<(S + 255) / 256, 256, 0, stream>>>(score32, n1, p32, keepI, alphaPtr, n1, n2, sent, N, S);
    k_scanA<<<nb, 256, 0, stream>>>(keepI, bs, N);
    k_scanB<<<1, 256, 0, stream>>>(bs, bo, nb);
    k_scanC<<<nb, 256, 0, stream>>>(keepI, bo, tg, posF, gate, o_keep, N);

    long total4 = (long)N * (C / 4);
    int nxb = (int)((total4 + 255) / 256);
    long e4 = (E + 3) / 4;
    int neb4 = (int)((e4 + 255) / 256);
    int nsb = (S + 255) / 256;
    k_out<<<nxb + neb4 + nsb, 256, 0, stream>>>(
        (const float4*)x, gate, o_x, total4,
        erow, ecol, posF, o_edge, o_ekeep, E,
        n1, n2, sent, o_n1, o_n2, o_sent, S, nxb, neb4);
}